// Round 7
// baseline (269.000 us; speedup 1.0000x reference)
//
#include <hip/hip_runtime.h>
#include <math.h>

// EdgeGAT: B=8, OP=400, MA=200, F=64. f32 in/out, adj int32.
// Barrier-free flash split: one WAVE per 32-row chunk (13 chunks per (b,m)).
// Adjacency pre-packed to 32-bit masks; scores quad-layout + DPP reduce;
// M/L lane-butterfly; v/u lane=feature with L2 re-read. Zero __syncthreads
// in the hot kernel.
#define B_   8
#define OP_  400
#define MA_  200
#define NCH  13           // ceil(400/32) chunks per (b,m) row
#define CHW  32           // rows per wave-chunk
#define PSTR 132          // partial stride: v[64] u[64] M L (+2 pad)
#define NEGM -1.0e30f     // finite mask sentinel
#define NW   (B_ * MA_ * NCH)   // 20800 wave-chunks

typedef unsigned int u32;

// ---------------- kernel 1: precompute ----------------
// blocks < 1200: w_e = W_edge@a_edge ; e_op[b,n] ; e_ma[b,m]  (wave per row)
// blocks >= 1200: pack adjT into per-(b,m,chunk) 32-bit masks
__global__ __launch_bounds__(256) void precompute_k(
    const float* __restrict__ x, const float* __restrict__ y,
    const int* __restrict__ adj,
    const float* __restrict__ Wop, const float* __restrict__ Wma,
    const float* __restrict__ Wedge, const float* __restrict__ att,
    float* __restrict__ ws_we, float* __restrict__ ws_eop,
    float* __restrict__ ws_ema, u32* __restrict__ msk)
{
    const int tid = threadIdx.x, wv = tid >> 6, ln = tid & 63;

    if (blockIdx.x >= 1200) {          // ---- mask packing ----
        const int w = (blockIdx.x - 1200) * 256 + tid;
        if (w < NW) {
            const int bm = w / NCH, c = w % NCH;
            const int b = bm / MA_, m = bm % MA_;
            u32 mk = 0;
            #pragma unroll 8
            for (int j = 0; j < CHW; ++j) {
                const int n = c * CHW + j;
                if (n < OP_ && adj[((size_t)(b * OP_ + n)) * MA_ + m] != 0)
                    mk |= (1u << j);
            }
            msk[w] = mk;
        }
        return;
    }

    __shared__ float w_s[192];
    if (tid < 192) {
        const int which = tid >> 6, i = tid & 63;
        const float* W = (which == 0) ? Wop : ((which == 1) ? Wma : Wedge);
        const float* a = att + which * 64;
        float acc = 0.f;
        #pragma unroll 8
        for (int f = 0; f < 64; ++f) acc = fmaf(W[i * 64 + f], a[f], acc);
        w_s[tid] = acc;
    }
    __syncthreads();
    if (blockIdx.x == 0 && tid < 64) ws_we[tid] = w_s[128 + tid];

    const int row = blockIdx.x * 4 + wv;           // 0 .. 4799
    if (row < B_ * OP_) {
        float s = x[(size_t)row * 64 + ln] * w_s[ln];
        #pragma unroll
        for (int o = 32; o > 0; o >>= 1) s += __shfl_xor(s, o, 64);
        if (ln == 0) ws_eop[row] = s;
    } else if (row < B_ * OP_ + B_ * MA_) {
        const int r2 = row - B_ * OP_;
        float s = y[(size_t)r2 * 64 + ln] * w_s[64 + ln];
        #pragma unroll
        for (int o = 32; o > 0; o >>= 1) s += __shfl_xor(s, o, 64);
        if (ln == 0) ws_ema[r2] = s;
    }
}

// ---------------- kernel 2: barrier-free chunk partials (wave = (b,m,chunk)) ----------------
__global__ __launch_bounds__(256) void gat_chunk(
    const float* __restrict__ x, const float* __restrict__ z,
    const u32* __restrict__ msk,
    const float* __restrict__ ws_we, const float* __restrict__ ws_eop,
    const float* __restrict__ ws_ema, float* __restrict__ part)
{
    __shared__ float sw[4][CHW];       // per-wave scores
    __shared__ float sp[4][CHW];       // per-wave softmax numerators

    const int tid = threadIdx.x, wv = tid >> 6, ln = tid & 63;
    const int wid = blockIdx.x * 4 + wv;          // 0 .. NW-1
    const int bm = wid / NCH, c = wid % NCH;
    const int b = bm / MA_, m = bm % MA_;
    const int n0 = c * CHW;

    const u32 mask = msk[wid];                    // wave-uniform, 1 load
    const float emav = ws_ema[bm];

    // w_e segment for this lane's quad position
    const int r = ln >> 2, g = ln & 3;
    const float4* wep = (const float4*)(ws_we + g * 16);
    const float4 w0 = wep[0], w1 = wep[1], w2 = wep[2], w3 = wep[3];

    const float* zrow0 = z + ((size_t)(b * OP_ + n0) * MA_ + m) * 64;
    const float* xrow0 = x + (size_t)(b * OP_ + n0) * 64;

    // ---- scores: quad-per-row, 2 batches of 16 rows ----
    #pragma unroll
    for (int bt = 0; bt < 2; ++bt) {
        const int j = bt * 16 + r;                // bit / local row index
        const bool a = (mask >> j) & 1u;          // set only when n0+j < OP_
        float s = 0.f;
        float res = NEGM;
        if (a) {
            const float4* zr = (const float4*)(zrow0 + (size_t)j * (MA_ * 64) + g * 16);
            const float4 q0 = zr[0], q1 = zr[1], q2 = zr[2], q3 = zr[3];
            s = fmaf(q0.x, w0.x, fmaf(q0.y, w0.y, fmaf(q0.z, w0.z, q0.w * w0.w)));
            s = fmaf(q1.x, w1.x, fmaf(q1.y, w1.y, fmaf(q1.z, w1.z, fmaf(q1.w, w1.w, s))));
            s = fmaf(q2.x, w2.x, fmaf(q2.y, w2.y, fmaf(q2.z, w2.z, fmaf(q2.w, w2.w, s))));
            s = fmaf(q3.x, w3.x, fmaf(q3.y, w3.y, fmaf(q3.z, w3.z, fmaf(q3.w, w3.w, s))));
        }
        s += __shfl_xor(s, 1, 64);                // quad_perm DPP (VALU)
        s += __shfl_xor(s, 2, 64);
        if (a) {
            const float e = s + ws_eop[b * OP_ + n0 + j] + emav;
            res = (e >= 0.f) ? e : 0.01f * e;     // leaky_relu
        }
        if (g == 0) sw[wv][j] = res;
    }

    // ---- wave softmax over 32 scores (lanes 0..31; butterflies stay in-group) ----
    const float sl = (ln < CHW) ? sw[wv][ln] : NEGM;   // same-wave LDS, lgkmcnt only
    float M = sl;
    M = fmaxf(M, __shfl_xor(M, 1, 64));
    M = fmaxf(M, __shfl_xor(M, 2, 64));
    M = fmaxf(M, __shfl_xor(M, 4, 64));
    M = fmaxf(M, __shfl_xor(M, 8, 64));
    M = fmaxf(M, __shfl_xor(M, 16, 64));
    // empty chunk: M==NEGM -> p=exp(0)=1, L=32, but combine zeroes it via Mc guard
    float p = (ln < CHW) ? __expf(sl - M) : 0.f;
    float L = p;
    L += __shfl_xor(L, 1, 64);
    L += __shfl_xor(L, 2, 64);
    L += __shfl_xor(L, 4, 64);
    L += __shfl_xor(L, 8, 64);
    L += __shfl_xor(L, 16, 64);
    if (ln < CHW) sp[wv][ln] = p;

    // ---- v/u: lane = feature; active rows only (z re-read hits L2) ----
    float v = 0.f, u = 0.f;
    #pragma unroll
    for (int j = 0; j < CHW; ++j) {
        if ((mask >> j) & 1u) {                   // wave-uniform branch
            const float pj = sp[wv][j];           // LDS broadcast
            v = fmaf(pj, zrow0[(size_t)j * (MA_ * 64) + ln], v);
            u = fmaf(pj, xrow0[(size_t)j * 64 + ln], u);
        }
    }

    // ---- write partial: v[64] u[64] M L (single wave owns the chunk) ----
    float* pp = part + (size_t)wid * PSTR;
    pp[ln]      = v;
    pp[64 + ln] = u;
    if (ln == 0) { pp[128] = M; pp[129] = L; }
}

// ---------------- kernel 3: combine + epilogue (wave per (b,m) row) ----------------
__global__ __launch_bounds__(256) void gat_combine(
    const float* __restrict__ y,
    const float* __restrict__ Wop, const float* __restrict__ Wma,
    const float* __restrict__ Wedge,
    const float* __restrict__ part, float* __restrict__ out)
{
    __shared__ float vs[4][64], us[4][64], ys[4][64];
    const int tid = threadIdx.x, wv = tid >> 6, ln = tid & 63;
    const int row = blockIdx.x * 4 + wv;        // bm, grid covers 1600 exactly

    const float* pp = part + (size_t)row * NCH * PSTR;
    float M = NEGM;
    #pragma unroll
    for (int c = 0; c < NCH; ++c) M = fmaxf(M, pp[c * PSTR + 128]);
    float L = 0.f, v = 0.f, u = 0.f;
    #pragma unroll
    for (int c = 0; c < NCH; ++c) {
        const float Mc = pp[c * PSTR + 128];
        const float w  = (Mc > -1.0e29f) ? __expf(Mc - M) : 0.f;
        L += w * pp[c * PSTR + 129];
        v += w * pp[c * PSTR + ln];
        u += w * pp[c * PSTR + 64 + ln];
    }
    const float inv = (L > 0.f) ? (1.f / L) : 0.f;
    vs[wv][ln] = v * inv;
    us[wv][ln] = u * inv;
    ys[wv][ln] = y[(size_t)row * 64 + ln];
    __syncthreads();

    float hv = 0.f;
    #pragma unroll 8
    for (int i = 0; i < 64; ++i) {
        hv += vs[wv][i] * Wedge[i * 64 + ln]
            + us[wv][i] * Wop[i * 64 + ln]
            + ys[wv][i] * Wma[i * 64 + ln];
    }
    out[(size_t)row * 64 + ln] = (hv > 0.f) ? hv : (__expf(hv) - 1.f);
}

extern "C" void kernel_launch(void* const* d_in, const int* in_sizes, int n_in,
                              void* d_out, int out_size, void* d_ws, size_t ws_size,
                              hipStream_t stream) {
    const float* x     = (const float*)d_in[0];
    const float* y     = (const float*)d_in[1];
    const float* z     = (const float*)d_in[2];
    const int*   adj   = (const int*)d_in[3];
    const float* Wop   = (const float*)d_in[4];
    const float* Wma   = (const float*)d_in[5];
    const float* Wedge = (const float*)d_in[6];
    const float* att   = (const float*)d_in[7];

    float* ws     = (float*)d_ws;
    float* ws_we  = ws;                              // 64
    float* ws_eop = ws + 64;                         // B*OP = 3200
    float* ws_ema = ws + 64 + B_ * OP_;              // B*MA = 1600
    float* part   = ws + 4864;                       // NW * PSTR = 2,745,600
    u32*   msk    = (u32*)(ws + 4864 + (size_t)NW * PSTR);  // NW words

    const int maskBlocks = (NW + 255) / 256;         // 82
    precompute_k<<<1200 + maskBlocks, 256, 0, stream>>>(
        x, y, adj, Wop, Wma, Wedge, att, ws_we, ws_eop, ws_ema, msk);
    gat_chunk<<<NW / 4, 256, 0, stream>>>(
        x, z, msk, ws_we, ws_eop, ws_ema, part);
    gat_combine<<<(B_ * MA_) / 4, 256, 0, stream>>>(
        y, Wop, Wma, Wedge, part, (float*)d_out);
}